// Round 1
// baseline (178.595 us; speedup 1.0000x reference)
//
#include <hip/hip_runtime.h>
#include <cstdint>

#define NEGV (-10000.0f)

typedef short bf16x8 __attribute__((ext_vector_type(8)));
typedef float f32x4 __attribute__((ext_vector_type(4)));

__device__ __forceinline__ short f2bf(float f) {
  union { float f; uint32_t u; } v; v.f = f;
  uint32_t u = v.u + 0x7fffu + ((v.u >> 16) & 1u);
  return (short)(u >> 16);
}
__device__ __forceinline__ float b2f(short s) {
  union { uint32_t u; float f; } v; v.u = ((uint32_t)(uint16_t)s) << 16;
  return v.f;
}

// ---------------- P1: weight combine + bf16 casts ----------------
// Wk[h][d] = W1[h][128+d] - W1[h][256+d]   (bf16, 256x128)
// Wd[h][d] = W1[h][384+d]                  (bf16, 256x128)
// W2b      = bf16(W2)                      (128x256)
__global__ void prep_weights(const float* __restrict__ W1, const float* __restrict__ W2,
                             short* __restrict__ Wk, short* __restrict__ Wd,
                             short* __restrict__ W2b) {
  int idx = blockIdx.x * 256 + threadIdx.x;
  if (idx < 32768) {
    int h = idx >> 7, d = idx & 127;
    Wk[idx] = f2bf(W1[h * 512 + 128 + d] - W1[h * 512 + 256 + d]);
  } else if (idx < 65536) {
    int i = idx - 32768;
    int h = i >> 7, d = i & 127;
    Wd[i] = f2bf(W1[h * 512 + 384 + d]);
  } else {
    int i = idx - 65536;
    W2b[i] = f2bf(W2[i]);
  }
}

// ---------------- P2: U[b][h] = b1[h] + sum_d (W1[h][d]+W1[h][256+d]) * q[b][d] ----
__global__ void prep_u(const float* __restrict__ query, const float* __restrict__ W1,
                       const float* __restrict__ b1, float* __restrict__ U) {
  __shared__ float q8[8][128];
  int tid = threadIdx.x;
  int b0 = blockIdx.x * 8;
  for (int i = tid; i < 1024; i += 256)
    q8[i >> 7][i & 127] = query[(size_t)(b0 + (i >> 7)) * 128 + (i & 127)];
  __syncthreads();
  int h = tid;
  const float4* w0 = (const float4*)(W1 + (size_t)h * 512);
  const float4* w1 = (const float4*)(W1 + (size_t)h * 512 + 256);
  float acc[8];
  float bb = b1[h];
#pragma unroll
  for (int i = 0; i < 8; ++i) acc[i] = bb;
  for (int d4 = 0; d4 < 32; ++d4) {
    float4 wa = w0[d4], wb = w1[d4];
    float wv0 = wa.x + wb.x, wv1 = wa.y + wb.y, wv2 = wa.z + wb.z, wv3 = wa.w + wb.w;
#pragma unroll
    for (int i = 0; i < 8; ++i) {
      float4 qv = ((const float4*)q8[i])[d4];
      acc[i] += wv0 * qv.x + wv1 * qv.y + wv2 * qv.z + wv3 * qv.w;
    }
  }
#pragma unroll
  for (int i = 0; i < 8; ++i) U[(size_t)(b0 + i) * 256 + h] = acc[i];
}

// ---------------- main: one block per batch row ----------------
__global__ __launch_bounds__(256, 2) void din_main(
    const float* __restrict__ query, const float* __restrict__ keys,
    const int* __restrict__ mask,
    const float* __restrict__ b2p, const float* __restrict__ a1p,
    const float* __restrict__ a2p, const float* __restrict__ W3,
    const float* __restrict__ b3p,
    const float* __restrict__ U, const short* __restrict__ Wk,
    const short* __restrict__ Wd, const short* __restrict__ W2b,
    float* __restrict__ out) {
  __shared__ short Kl[208 * 128];   // bf16 keys, XOR-swizzled rows (256B stride)
  __shared__ short H1[16 * 256];    // bf16 h1 tile, XOR-swizzled rows (512B stride)
  __shared__ float scores[208];
  __shared__ float wl[208];
  __shared__ float red[8];
  __shared__ float opart[128];

  const int tid = threadIdx.x;
  const int b = blockIdx.x;
  const int lane = tid & 63, wid = tid >> 6;
  const int lr = lane & 15;   // row/col within 16-tile
  const int lg = lane >> 4;   // k-group (0..3)

  const float a1 = a1p[0], a2 = a2p[0], b3 = b3p[0];

  // ---- stage keys -> bf16 LDS (swizzled), init scores ----
  for (int it = tid; it < 208 * 16; it += 256) {
    int l = it >> 4, c8 = it & 15;
    bf16x8 v;
    if (l < 200) {
      const float4* kp = (const float4*)(keys + ((size_t)b * 200 + l) * 128 + c8 * 8);
      float4 x0 = kp[0], x1 = kp[1];
      v[0] = f2bf(x0.x); v[1] = f2bf(x0.y); v[2] = f2bf(x0.z); v[3] = f2bf(x0.w);
      v[4] = f2bf(x1.x); v[5] = f2bf(x1.y); v[6] = f2bf(x1.z); v[7] = f2bf(x1.w);
    } else {
#pragma unroll
      for (int j = 0; j < 8; ++j) v[j] = 0;
    }
    *(bf16x8*)(&Kl[l * 128 + ((c8 * 8) ^ ((l & 7) << 3))]) = v;
  }
  if (tid < 208) scores[tid] = b3;

  // ---- persistent register fragments ----
  // GEMM1 B-operand: M_b[h][d] = Wk[h][d] + Wd[h][d]*q[d]; B[k=d][n=h]
  bf16x8 mf[4][4];  // [nt][ks]
  float uval[4];
  {
    const float* qrow = query + (size_t)b * 128;
#pragma unroll
    for (int nt = 0; nt < 4; ++nt) {
      int h = wid * 64 + nt * 16 + lr;
      uval[nt] = U[(size_t)b * 256 + h];
#pragma unroll
      for (int ks = 0; ks < 4; ++ks) {
        int d0 = ks * 32 + lg * 8;
        bf16x8 wk = *(const bf16x8*)(Wk + h * 128 + d0);
        bf16x8 wd = *(const bf16x8*)(Wd + h * 128 + d0);
        float4 q0 = *(const float4*)(qrow + d0);
        float4 q1 = *(const float4*)(qrow + d0 + 4);
        float qv[8] = {q0.x, q0.y, q0.z, q0.w, q1.x, q1.y, q1.z, q1.w};
        bf16x8 r;
#pragma unroll
        for (int j = 0; j < 8; ++j) r[j] = f2bf(b2f(wk[j]) + b2f(wd[j]) * qv[j]);
        mf[nt][ks] = r;
      }
    }
  }
  // GEMM2 B-operand: W2[g][h]; B[k=h][n=g]
  bf16x8 w2f[2][8];
  float b2v[2], w3v[2];
#pragma unroll
  for (int nt = 0; nt < 2; ++nt) {
    int g = wid * 32 + nt * 16 + lr;
    b2v[nt] = b2p[g];
    w3v[nt] = W3[g];
#pragma unroll
    for (int ks = 0; ks < 8; ++ks)
      w2f[nt][ks] = *(const bf16x8*)(W2b + g * 256 + ks * 32 + lg * 8);
  }
  __syncthreads();

  // ---- 13 M-tiles of 16 rows ----
  for (int mt = 0; mt < 13; ++mt) {
    // A-fragments from swizzled K LDS
    const int al = mt * 16 + lr;
    bf16x8 af[4];
#pragma unroll
    for (int ks = 0; ks < 4; ++ks)
      af[ks] = *(const bf16x8*)(&Kl[al * 128 + ((ks * 32 + lg * 8) ^ ((al & 7) << 3))]);

    f32x4 acc1[4];
#pragma unroll
    for (int nt = 0; nt < 4; ++nt)
#pragma unroll
      for (int r = 0; r < 4; ++r) acc1[nt][r] = 0.f;
#pragma unroll
    for (int ks = 0; ks < 4; ++ks)
#pragma unroll
      for (int nt = 0; nt < 4; ++nt)
        acc1[nt] = __builtin_amdgcn_mfma_f32_16x16x32_bf16(af[ks], mf[nt][ks], acc1[nt], 0, 0, 0);

    // epilogue1: +u, PReLU(a1), -> H1 (bf16, swizzled)
#pragma unroll
    for (int nt = 0; nt < 4; ++nt) {
      int col = wid * 64 + nt * 16 + lr;
#pragma unroll
      for (int r = 0; r < 4; ++r) {
        int row = lg * 4 + r;
        float v = acc1[nt][r] + uval[nt];
        v = (v >= 0.f) ? v : a1 * v;
        H1[row * 256 + (col ^ ((row & 7) << 3))] = f2bf(v);
      }
    }
    __syncthreads();

    // GEMM2: h2[l][g] = sum_h H1[l][h] * W2[g][h]
    f32x4 acc2[2];
#pragma unroll
    for (int nt = 0; nt < 2; ++nt)
#pragma unroll
      for (int r = 0; r < 4; ++r) acc2[nt][r] = 0.f;
#pragma unroll
    for (int ks = 0; ks < 8; ++ks) {
      bf16x8 a2f = *(const bf16x8*)(&H1[lr * 256 + ((ks * 32 + lg * 8) ^ ((lr & 7) << 3))]);
      acc2[0] = __builtin_amdgcn_mfma_f32_16x16x32_bf16(a2f, w2f[0][ks], acc2[0], 0, 0, 0);
      acc2[1] = __builtin_amdgcn_mfma_f32_16x16x32_bf16(a2f, w2f[1][ks], acc2[1], 0, 0, 0);
    }

    // epilogue2: +b2, PReLU(a2), * W3, reduce over g
    float sp[4];
#pragma unroll
    for (int r = 0; r < 4; ++r) {
      float s = 0.f;
#pragma unroll
      for (int nt = 0; nt < 2; ++nt) {
        float v = acc2[nt][r] + b2v[nt];
        v = (v >= 0.f) ? v : a2 * v;
        s += v * w3v[nt];
      }
      sp[r] = s;
    }
#pragma unroll
    for (int m = 1; m < 16; m <<= 1)
#pragma unroll
      for (int r = 0; r < 4; ++r) sp[r] += __shfl_xor(sp[r], m);
    if (lr == 0) {
#pragma unroll
      for (int r = 0; r < 4; ++r) atomicAdd(&scores[mt * 16 + lg * 4 + r], sp[r]);
    }
    __syncthreads();
  }

  // ---- masked softmax over L=200 (fp32) ----
  float val = NEGV;
  int mk = 0;
  if (tid < 200) {
    mk = mask[(size_t)b * 200 + tid];
    float sc = scores[tid];
    val = mk ? sc : NEGV;
  }
  float m = val;
#pragma unroll
  for (int off = 1; off < 64; off <<= 1) m = fmaxf(m, __shfl_xor(m, off));
  if ((tid & 63) == 0) red[tid >> 6] = m;
  __syncthreads();
  float smax = fmaxf(fmaxf(red[0], red[1]), fmaxf(red[2], red[3]));
  float p = (tid < 200 && mk) ? __expf(val - smax) : 0.f;
  float s = p;
#pragma unroll
  for (int off = 1; off < 64; off <<= 1) s += __shfl_xor(s, off);
  if ((tid & 63) == 0) red[4 + (tid >> 6)] = s;
  __syncthreads();
  float ssum = red[4] + red[5] + red[6] + red[7];
  float winv = (ssum > 0.f) ? 1.f / ssum : 0.f;
  if (tid < 208) wl[tid] = (tid < 200) ? p * winv : 0.f;
  __syncthreads();

  // ---- weighted sum: out[b][d] = sum_l w[l] * keys[b][l][d] (bf16 keys from LDS) ----
  const int d = tid & 127, half = tid >> 7;
  float acc = 0.f;
  for (int l = half; l < 200; l += 2) {
    float wv = wl[l];
    if (wv != 0.f) {
      short kv = Kl[l * 128 + (d ^ ((l & 7) << 3))];
      acc += wv * b2f(kv);
    }
  }
  if (half) opart[d] = acc;
  __syncthreads();
  if (!half) out[(size_t)b * 128 + d] = acc + opart[d];
}

extern "C" void kernel_launch(void* const* d_in, const int* in_sizes, int n_in,
                              void* d_out, int out_size, void* d_ws, size_t ws_size,
                              hipStream_t stream) {
  const float* query = (const float*)d_in[0];
  const float* keys  = (const float*)d_in[1];
  const int*   maskp = (const int*)d_in[2];
  const float* W1    = (const float*)d_in[3];
  const float* b1    = (const float*)d_in[4];
  const float* a1    = (const float*)d_in[5];
  const float* W2    = (const float*)d_in[6];
  const float* b2    = (const float*)d_in[7];
  const float* a2    = (const float*)d_in[8];
  const float* W3    = (const float*)d_in[9];
  const float* b3    = (const float*)d_in[10];
  float* out = (float*)d_out;

  // workspace layout
  float* U   = (float*)d_ws;                         // 2048*256*4 = 2 MiB
  short* Wk  = (short*)((char*)d_ws + 2097152);      // 64 KiB
  short* Wd  = Wk + 32768;                           // 64 KiB
  short* W2b = Wd + 32768;                           // 64 KiB

  prep_weights<<<384, 256, 0, stream>>>(W1, W2, Wk, Wd, W2b);
  prep_u<<<256, 256, 0, stream>>>(query, W1, b1, U);
  din_main<<<2048, 256, 0, stream>>>(query, keys, maskp, b2, a1, a2, W3, b3,
                                     U, Wk, Wd, W2b, out);
}